// Round 9
// baseline (3805.439 us; speedup 1.0000x reference)
//
#include <hip/hip_runtime.h>
#include <hip/hip_bf16.h>
#include <cstdint>

#define T_ 512
#define B_ 1024
#define D_ 6
#define H_ 128
#define CH_ 8   // chunk timesteps

typedef _Float16 f16;
typedef _Float16 f16x8 __attribute__((ext_vector_type(8)));
typedef float f32x4 __attribute__((ext_vector_type(4)));

// branch-free erf (Abramowitz-Stegun 7.1.26, max abs err 1.5e-7)
__device__ __forceinline__ float erf_f(float x) {
    float ax = fabsf(x);
    float t = __builtin_amdgcn_rcpf(fmaf(0.3275911f, ax, 1.f));
    float p = fmaf(t, 1.061405429f, -1.453152027f);
    p = fmaf(t, p, 1.421413741f);
    p = fmaf(t, p, -0.284496736f);
    p = fmaf(t, p, 0.254829592f);
    p = p * t;
    float e = __builtin_amdgcn_exp2f(-ax * ax * 1.4426950408889634f);
    float r = 1.f - p * e;
    return copysignf(r, x);
}
__device__ __forceinline__ float gelu_f(float x) {
    return 0.5f * x * (1.f + erf_f(x * 0.7071067811865476f));
}
__device__ __forceinline__ float sig_f(float x) {
    return __builtin_amdgcn_rcpf(1.f + __builtin_amdgcn_exp2f(-1.4426950408889634f * x));
}
__device__ __forceinline__ float tanh_f(float x) {
    return 2.f * sig_f(2.f * x) - 1.f;
}
__device__ __forceinline__ f16x8 load8cvt(const float* p) {
    float4 a = ((const float4*)p)[0];
    float4 b = ((const float4*)p)[1];
    f16x8 r = { (f16)a.x, (f16)a.y, (f16)a.z, (f16)a.w,
                (f16)b.x, (f16)b.y, (f16)b.z, (f16)b.w };
    return r;
}
// LICM-defeating pointer launder: makes weight loads loop-variant so they are
// per-use L2 reads (phase-local live range) instead of hoisted-then-spilled
// registers (R8: 214MB spill writes / 3.8GB refills from exactly this).
__device__ __forceinline__ const float* launder(const float* p) {
    asm volatile("" : "+s"(p));
    return p;
}
// LDS tiles: row-major [rows][128] f16, 256B row stride, 16B-chunk XOR swizzle
__device__ __forceinline__ f16x8 lds_rd8(const f16* base, int row, int cb) {
    const char* p = (const char*)base + row * 256 + (cb ^ ((row & 7) << 4));
    return *(const f16x8*)p;
}
__device__ __forceinline__ void lds_wr1(f16* base, int row, int col, f16 v) {
    char* p = (char*)base + row * 256 + ((col * 2) ^ ((row & 7) << 4));
    *(f16*)p = v;
}
// ZX tile: [32 rows][512 cols] f16, 1024B row stride, same XOR swizzle
__device__ __forceinline__ void zx_wr(f16* base, int row, int col, f16 v) {
    char* p = (char*)base + row * 1024 + ((col * 2) ^ ((row & 7) << 4));
    *(f16*)p = v;
}
__device__ __forceinline__ float zx_rd(const f16* base, int row, int col) {
    const char* p = (const char*)base + row * 1024 + ((col * 2) ^ ((row & 7) << 4));
    return (float)*(const f16*)p;
}

// ---------------------------------------------------------------------------
// K1: FULLY FUSED conv stack + LSTM0 + LSTM1 (one-chunk lag). 256 blocks x
// 512 threads, 4 batch rows/block. Per chunk of 8 steps:
//   P0: conv L0 (VALU) -> XA0.
//   P1-P3: conv L1..L3 MFMA, B streamed from global via laundered pointers.
//   P4a: ZX0 = x @ Wih0^T.  P4b: ZX1 = YH(prev chunk) @ Wih1^T.
//   P5a: 8 lstm0 slots (whh0 resident, 64 frag regs) -> YH.
//   P5b: 8 lstm1 slots; whh1 frags reloaded per chunk (phase-local 64 regs).
// Peak reg demand ~134 << 256 unified budget. WRITE_SIZE is the spill
// tripwire (legit writes = hfin 512KB only).
// ---------------------------------------------------------------------------
__global__ __launch_bounds__(512) void fused_all_k(
    const float* __restrict__ src,
    const float* __restrict__ w0p, const float* __restrict__ b0p,
    const float* __restrict__ w1p, const float* __restrict__ b1p,
    const float* __restrict__ w2p, const float* __restrict__ b2p,
    const float* __restrict__ w3p, const float* __restrict__ b3p,
    const float* __restrict__ posp,
    const float* __restrict__ Wih0, const float* __restrict__ Whh0,
    const float* __restrict__ bih0, const float* __restrict__ bhh0,
    const float* __restrict__ Wih1, const float* __restrict__ Whh1,
    const float* __restrict__ bih1, const float* __restrict__ bhh1,
    float* __restrict__ hfin)
{
    __shared__ f16 XA0[32 * 128];         // 8KB token tile ping
    __shared__ f16 XA1[32 * 128];         // 8KB token tile pong
    __shared__ f16 ZX0[32 * 512];         // 32KB z_x lstm0
    __shared__ f16 ZX1[32 * 512];         // 32KB z_x lstm1
    __shared__ f16 YH[32 * 128];          // 8KB h0 history (single buffer:
                                          //  read at P4b before P5a rewrites)
    __shared__ f16 HL0[2][4 * 128];       // 2KB h0 dbuf
    __shared__ f16 HL1[2][4 * 128];       // 2KB h1 dbuf   => 92KB total

    const int tid = threadIdx.x;
    const int lane = tid & 63, wid = tid >> 6;
    const int l16 = lane & 15, hi = lane >> 4;
    const int bb0 = blockIdx.x * 4;
    const int mycol = wid * 16 + l16;

    // lstm0 h-side frags resident (64 regs, AGPR-eligible); lstm1's are
    // reloaded per chunk in P5b. Biases are scalars, kept resident.
    f16x8 whh0[4][4];
    float bg0[4], bg1[4];
#pragma unroll
    for (int g = 0; g < 4; ++g) {
        int n = g * 128 + mycol;
        bg0[g] = bih0[n] + bhh0[n];
        bg1[g] = bih1[n] + bhh1[n];
#pragma unroll
        for (int ki = 0; ki < 4; ++ki)
            whh0[g][ki] = load8cvt(Whh0 + n * 128 + ki * 32 + hi * 8);
    }

    // conv layer0 per-thread slice + conv biases
    const int col0 = tid & 127;
    const int r0 = tid >> 7;
    float w0c[6], b0c;
#pragma unroll
    for (int k = 0; k < 6; ++k) w0c[k] = w0p[col0 * 6 + k];
    b0c = b0p[col0];
    const float b1c = b1p[mycol], b2c = b2p[mycol], b3c = b3p[mycol];

    for (int i = tid; i < 2 * 4 * 128; i += 512) {
        ((f16*)HL0)[i] = (f16)0.f;
        ((f16*)HL1)[i] = (f16)0.f;
    }

    float c0 = 0.f, h0 = 0.f, c1 = 0.f, h1 = 0.f;
    __syncthreads();

    // conv MFMA layer: A from LDS, B streamed via laundered global pointer
    auto conv_mfma = [&](const f16* Xin, f16* Xout, const float* Wg0, float bc, int t0pos) {
        const float* Wg = launder(Wg0);
        f16x8 bf[4];
#pragma unroll
        for (int ki = 0; ki < 4; ++ki)
            bf[ki] = load8cvt(Wg + mycol * 128 + ki * 32 + hi * 8);
#pragma unroll
        for (int mt = 0; mt < 2; ++mt) {
            f16x8 af[4];
#pragma unroll
            for (int ki = 0; ki < 4; ++ki)
                af[ki] = lds_rd8(Xin, mt * 16 + l16, ki * 64 + hi * 16);
            f32x4 acc = { bc, bc, bc, bc };
#pragma unroll
            for (int ki = 0; ki < 4; ++ki)
                acc = __builtin_amdgcn_mfma_f32_16x16x32_f16(af[ki], bf[ki], acc, 0, 0, 0);
            float pv = 0.f;
            if (t0pos >= 0) pv = posp[(t0pos + mt * 4 + hi) * 128 + mycol];
#pragma unroll
            for (int j = 0; j < 4; ++j)
                lds_wr1(Xout, mt * 16 + hi * 4 + j, mycol, (f16)(gelu_f(acc[j]) + pv));
        }
    };

    // z = A(32x128 LDS) @ Wg^T(512x128 global, laundered) -> ZXout (f16)
    auto zgemm = [&](const f16* Ain, const float* Wg0, f16* ZXout) {
        const float* Wg = launder(Wg0);
        f16x8 af[2][4];
#pragma unroll
        for (int mt = 0; mt < 2; ++mt)
#pragma unroll
            for (int ki = 0; ki < 4; ++ki)
                af[mt][ki] = lds_rd8(Ain, mt * 16 + l16, ki * 64 + hi * 16);
#pragma unroll
        for (int nt = 0; nt < 4; ++nt) {
            const int n = wid * 64 + nt * 16 + l16;
            f16x8 bf[4];
#pragma unroll
            for (int ki = 0; ki < 4; ++ki)
                bf[ki] = load8cvt(Wg + n * 128 + ki * 32 + hi * 8);
            f32x4 za0 = { 0.f, 0.f, 0.f, 0.f };
            f32x4 za1 = { 0.f, 0.f, 0.f, 0.f };
#pragma unroll
            for (int ki = 0; ki < 4; ++ki) {
                za0 = __builtin_amdgcn_mfma_f32_16x16x32_f16(af[0][ki], bf[ki], za0, 0, 0, 0);
                za1 = __builtin_amdgcn_mfma_f32_16x16x32_f16(af[1][ki], bf[ki], za1, 0, 0, 0);
            }
#pragma unroll
            for (int j = 0; j < 4; ++j) {
                zx_wr(ZXout, hi * 4 + j, wid * 64 + nt * 16 + l16, (f16)za0[j]);
                zx_wr(ZXout, 16 + hi * 4 + j, wid * 64 + nt * 16 + l16, (f16)za1[j]);
            }
            __builtin_amdgcn_sched_barrier(0);  // keep per-nt loads from hoisting
        }
    };

    // one LSTM step (h-side MFMA + pointwise); t parity selects HL buffer
    auto lstep = [&](f16 (*HLd)[4 * 128], int t, const f16x8 (&whf)[4][4],
                     const float (&bg)[4], const f16* ZXp, int it,
                     float& cc, float& hh, f16* yout) {
        f16x8 ha[4];
#pragma unroll
        for (int ki = 0; ki < 4; ++ki)
            ha[ki] = lds_rd8(HLd[t & 1], l16 >> 2, ki * 64 + hi * 16);
        f32x4 acc[4];
#pragma unroll
        for (int g = 0; g < 4; ++g) {
            f32x4 bv = { bg[g], bg[g], bg[g], bg[g] };
            acc[g] = bv;
        }
#pragma unroll
        for (int ki = 0; ki < 4; ++ki)
#pragma unroll
            for (int g = 0; g < 4; ++g)
                acc[g] = __builtin_amdgcn_mfma_f32_16x16x32_f16(ha[ki], whf[g][ki], acc[g], 0, 0, 0);
        float zi = acc[0][0] + zx_rd(ZXp, it * 4 + hi, 0 + mycol);
        float zf = acc[1][0] + zx_rd(ZXp, it * 4 + hi, 128 + mycol);
        float zg = acc[2][0] + zx_rd(ZXp, it * 4 + hi, 256 + mycol);
        float zo = acc[3][0] + zx_rd(ZXp, it * 4 + hi, 384 + mycol);
        cc = sig_f(zf) * cc + sig_f(zi) * tanh_f(zg);
        hh = sig_f(zo) * tanh_f(cc);
        lds_wr1(HLd[(t + 1) & 1], hi, mycol, (f16)hh);
        if (yout) lds_wr1(yout, it * 4 + hi, mycol, (f16)hh);
    };

    // per-chunk whh1 fragment reload (phase-local live range)
    auto load_whh1 = [&](f16x8 (&whf)[4][4]) {
        const float* Wp = launder(Whh1);
#pragma unroll
        for (int g = 0; g < 4; ++g)
#pragma unroll
            for (int ki = 0; ki < 4; ++ki)
                whf[g][ki] = load8cvt(Wp + (g * 128 + mycol) * 128 + ki * 32 + hi * 8);
    };

    for (int k = 0; k < T_ / CH_; ++k) {
        const int t0 = k * CH_;
        // --- P0: conv layer0 for 8 steps -> XA0 ---
        {
            const float2* sp0 = (const float2*)src + ((size_t)(bb0 + r0) * T_ + t0) * 3;
#pragma unroll
            for (int it = 0; it < CH_; ++it) {
                float2 a = sp0[it * 3 + 0], b = sp0[it * 3 + 1], c2 = sp0[it * 3 + 2];
                float acc = b0c;
                acc = fmaf(a.x, w0c[0], acc);
                acc = fmaf(a.y, w0c[1], acc);
                acc = fmaf(b.x, w0c[2], acc);
                acc = fmaf(b.y, w0c[3], acc);
                acc = fmaf(c2.x, w0c[4], acc);
                acc = fmaf(c2.y, w0c[5], acc);
                lds_wr1(XA0, it * 4 + r0, col0, (f16)gelu_f(acc));
            }
        }
        __syncthreads();
        // --- P1..P3: conv layers 1..3 ---
        conv_mfma(XA0, XA1, w1p, b1c, -1);
        __syncthreads();
        conv_mfma(XA1, XA0, w2p, b2c, -1);
        __syncthreads();
        conv_mfma(XA0, XA1, w3p, b3c, t0);   // + pos_embed
        __syncthreads();
        // --- P4a/P4b: z_x GEMMs; P4b reads YH (prev chunk) BEFORE P5a rewrites ---
        zgemm(XA1, Wih0, ZX0);
        if (k > 0) zgemm(YH, Wih1, ZX1);
        __syncthreads();
        // --- P5a: 8 lstm0 slots -> YH ---
        for (int it = 0; it < CH_; ++it) {
            lstep(HL0, t0 + it, whh0, bg0, ZX0, it, c0, h0, YH);
            __syncthreads();
        }
        // --- P5b: 8 lstm1 slots (lagged one chunk) ---
        if (k > 0) {
            f16x8 whh1f[4][4];
            load_whh1(whh1f);
            for (int it = 0; it < CH_; ++it) {
                lstep(HL1, t0 + it, whh1f, bg1, ZX1, it, c1, h1, nullptr);
                __syncthreads();
            }
        }
    }
    // --- tail: lstm1 on the last chunk's YH (steps 504..511) ---
    zgemm(YH, Wih1, ZX1);
    __syncthreads();
    {
        f16x8 whh1f[4][4];
        load_whh1(whh1f);
        for (int it = 0; it < CH_; ++it) {
            lstep(HL1, (T_ - CH_) + it, whh1f, bg1, ZX1, it, c1, h1, nullptr);
            __syncthreads();
        }
    }
    hfin[(size_t)(bb0 + hi) * H_ + mycol] = h1;
}

// ---------------------------------------------------------------------------
// K2: head — LayerNorm + Linear(128->32) + GELU + Linear(32->8). 4 rows/block.
// ---------------------------------------------------------------------------
__global__ __launch_bounds__(256) void head_k(
    const float* __restrict__ hfin,
    const float* __restrict__ lng, const float* __restrict__ lnb,
    const float* __restrict__ hw1, const float* __restrict__ hb1,
    const float* __restrict__ hw2, const float* __restrict__ hb2,
    float* __restrict__ outp)
{
    __shared__ float HN[4][128];
    __shared__ float G[4][32];
    const int tid = threadIdx.x, lane = tid & 63, wid = tid >> 6;
    const int b = blockIdx.x * 4 + wid;
    float v0 = hfin[b * 128 + lane], v1 = hfin[b * 128 + 64 + lane];
    float s = v0 + v1;
#pragma unroll
    for (int m = 1; m < 64; m <<= 1) s += __shfl_xor(s, m);
    float mu = s * (1.f / 128.f);
    float d0 = v0 - mu, d1 = v1 - mu;
    float q = d0 * d0 + d1 * d1;
#pragma unroll
    for (int m = 1; m < 64; m <<= 1) q += __shfl_xor(q, m);
    float rs = rsqrtf(q * (1.f / 128.f) + 1e-5f);
    HN[wid][lane] = d0 * rs * lng[lane] + lnb[lane];
    HN[wid][64 + lane] = d1 * rs * lng[64 + lane] + lnb[64 + lane];
    __syncthreads();
    if (tid < 128) {
        int row = tid >> 5, o = tid & 31;
        float a = hb1[o];
#pragma unroll 4
        for (int k = 0; k < 128; ++k) a = fmaf(HN[row][k], hw1[o * 128 + k], a);
        G[row][o] = gelu_f(a);
    }
    __syncthreads();
    if (tid < 32) {
        int row = tid >> 3, oo = tid & 7;
        float a = hb2[oo];
#pragma unroll
        for (int k = 0; k < 32; ++k) a = fmaf(G[row][k], hw2[oo * 32 + k], a);
        outp[(size_t)(blockIdx.x * 4 + row) * 8 + oo] = a;
    }
}

extern "C" void kernel_launch(void* const* d_in, const int* in_sizes, int n_in,
                              void* d_out, int out_size, void* d_ws, size_t ws_size,
                              hipStream_t stream) {
    (void)in_sizes; (void)n_in; (void)out_size; (void)ws_size;
    const float* src  = (const float*)d_in[0];
    const float* w0   = (const float*)d_in[1];
    const float* b0   = (const float*)d_in[2];
    const float* w1   = (const float*)d_in[3];
    const float* b1   = (const float*)d_in[4];
    const float* w2   = (const float*)d_in[5];
    const float* b2   = (const float*)d_in[6];
    const float* w3   = (const float*)d_in[7];
    const float* b3   = (const float*)d_in[8];
    const float* pos  = (const float*)d_in[9];
    const float* Wih0 = (const float*)d_in[10];
    const float* Whh0 = (const float*)d_in[11];
    const float* bih0 = (const float*)d_in[12];
    const float* bhh0 = (const float*)d_in[13];
    const float* Wih1 = (const float*)d_in[14];
    const float* Whh1 = (const float*)d_in[15];
    const float* bih1 = (const float*)d_in[16];
    const float* bhh1 = (const float*)d_in[17];
    const float* lng  = (const float*)d_in[18];
    const float* lnb  = (const float*)d_in[19];
    const float* hw1  = (const float*)d_in[20];
    const float* hb1  = (const float*)d_in[21];
    const float* hw2  = (const float*)d_in[22];
    const float* hb2  = (const float*)d_in[23];
    float* outp = (float*)d_out;

    float* hfin = (float*)d_ws;   // (B,H) f32 = 512KB

    fused_all_k<<<dim3(256), dim3(512), 0, stream>>>(
        src, w0, b0, w1, b1, w2, b2, w3, b3, pos,
        Wih0, Whh0, bih0, bhh0, Wih1, Whh1, bih1, bhh1, hfin);
    head_k<<<dim3(256), dim3(256), 0, stream>>>(
        hfin, lng, lnb, hw1, hb1, hw2, hb2, outp);
}

// Round 10
// 2388.644 us; speedup vs baseline: 1.5931x; 1.5931x over previous
//
#include <hip/hip_runtime.h>
#include <hip/hip_bf16.h>
#include <cstdint>

#define T_ 512
#define B_ 1024
#define D_ 6
#define H_ 128
#define CH_ 8   // chunk timesteps

typedef _Float16 f16;
typedef _Float16 f16x8 __attribute__((ext_vector_type(8)));
typedef float f32x4 __attribute__((ext_vector_type(4)));

// branch-free erf (Abramowitz-Stegun 7.1.26, max abs err 1.5e-7)
__device__ __forceinline__ float erf_f(float x) {
    float ax = fabsf(x);
    float t = __builtin_amdgcn_rcpf(fmaf(0.3275911f, ax, 1.f));
    float p = fmaf(t, 1.061405429f, -1.453152027f);
    p = fmaf(t, p, 1.421413741f);
    p = fmaf(t, p, -0.284496736f);
    p = fmaf(t, p, 0.254829592f);
    p = p * t;
    float e = __builtin_amdgcn_exp2f(-ax * ax * 1.4426950408889634f);
    float r = 1.f - p * e;
    return copysignf(r, x);
}
__device__ __forceinline__ float gelu_f(float x) {
    return 0.5f * x * (1.f + erf_f(x * 0.7071067811865476f));
}
__device__ __forceinline__ float sig_f(float x) {
    return __builtin_amdgcn_rcpf(1.f + __builtin_amdgcn_exp2f(-1.4426950408889634f * x));
}
__device__ __forceinline__ float tanh_f(float x) {
    return 2.f * sig_f(2.f * x) - 1.f;
}
__device__ __forceinline__ f16x8 load8cvt(const float* p) {
    float4 a = ((const float4*)p)[0];
    float4 b = ((const float4*)p)[1];
    f16x8 r = { (f16)a.x, (f16)a.y, (f16)a.z, (f16)a.w,
                (f16)b.x, (f16)b.y, (f16)b.z, (f16)b.w };
    return r;
}
// LICM-defeating pointer launder: ONLY for the two per-chunk-streamed zgemm
// weight pointers. R8: unlaundered streams got hoisted -> 304-reg demand ->
// 214MB spills. R9: laundering EVERYTHING re-streamed ~1MB/blk/chunk of fp32
// weights -> 1.7GB HBM. This round: resident frags for conv/whh (loaded once,
// no LICM issue), launder only Wih0/Wih1 f16 streams (512B/thread/chunk).
__device__ __forceinline__ const f16* launder16(const f16* p) {
    asm volatile("" : "+s"(p));
    return p;
}
// LDS tiles: row-major [rows][128] f16, 256B row stride, 16B-chunk XOR swizzle
__device__ __forceinline__ f16x8 lds_rd8(const f16* base, int row, int cb) {
    const char* p = (const char*)base + row * 256 + (cb ^ ((row & 7) << 4));
    return *(const f16x8*)p;
}
__device__ __forceinline__ void lds_wr1(f16* base, int row, int col, f16 v) {
    char* p = (char*)base + row * 256 + ((col * 2) ^ ((row & 7) << 4));
    *(f16*)p = v;
}
// ZX tile: [32 rows][512 cols] f16, 1024B row stride, same XOR swizzle
__device__ __forceinline__ void zx_wr(f16* base, int row, int col, f16 v) {
    char* p = (char*)base + row * 1024 + ((col * 2) ^ ((row & 7) << 4));
    *(f16*)p = v;
}
__device__ __forceinline__ float zx_rd(const f16* base, int row, int col) {
    const char* p = (const char*)base + row * 1024 + ((col * 2) ^ ((row & 7) << 4));
    return (float)*(const f16*)p;
}

// ---------------------------------------------------------------------------
// K0: prep — convert Wih0/Wih1 (512x128 f32) to f16 in ws.
// ---------------------------------------------------------------------------
__global__ __launch_bounds__(512) void prep_k(
    const float* __restrict__ Wih0, const float* __restrict__ Wih1,
    f16* __restrict__ w0f, f16* __restrict__ w1f)
{
    int i = blockIdx.x * 512 + threadIdx.x;   // 128 blocks x 512 = 65536
    w0f[i] = (f16)Wih0[i];
    w1f[i] = (f16)Wih1[i];
}

// ---------------------------------------------------------------------------
// K1: FULLY FUSED conv stack + LSTM0 + LSTM1 (one-chunk lag). 256 blocks x
// 512 threads, 4 batch rows/block. 13 barrier-phases per 8-step chunk
// (runtime law from R4-R9: dur ~ phases x ~2k cyc; this kills lstm1's
// 512 extra phases). Per chunk:
//   P0: conv L0 (VALU) -> XA0.
//   P1-P3: conv L1..L3 MFMA; B-frags RESIDENT in VGPRs (48, loaded once).
//   P4: ZX0 = x @ Wih0^T and ZX1 = YH(prev) @ Wih1^T; B streamed from f16
//       ws copies via laundered pointers (phase-local, 512B/thread/chunk).
//   P5 x8: lstm0(t)  AND lstm1(t-8) back-to-back (independent 4-deep MFMA
//       chains); whh0/whh1 resident (128 regs, AGPR-eligible).
// Reg demand ~216 < 256 unified budget. WRITE_SIZE = spill tripwire
// (legit global writes: hfin 512KB only).
// ---------------------------------------------------------------------------
__global__ __launch_bounds__(512) void fused_all_k(
    const float* __restrict__ src,
    const float* __restrict__ w0p, const float* __restrict__ b0p,
    const float* __restrict__ w1p, const float* __restrict__ b1p,
    const float* __restrict__ w2p, const float* __restrict__ b2p,
    const float* __restrict__ w3p, const float* __restrict__ b3p,
    const float* __restrict__ posp,
    const f16* __restrict__ Wih0f, const float* __restrict__ Whh0,
    const float* __restrict__ bih0, const float* __restrict__ bhh0,
    const f16* __restrict__ Wih1f, const float* __restrict__ Whh1,
    const float* __restrict__ bih1, const float* __restrict__ bhh1,
    float* __restrict__ hfin)
{
    __shared__ f16 XA0[32 * 128];         // 8KB token tile ping
    __shared__ f16 XA1[32 * 128];         // 8KB token tile pong
    __shared__ f16 ZX0[32 * 512];         // 32KB z_x lstm0
    __shared__ f16 ZX1[32 * 512];         // 32KB z_x lstm1
    __shared__ f16 YH[32 * 128];          // 8KB h0 history (read P4, write P5)
    __shared__ f16 HL0[2][4 * 128];       // 2KB h0 dbuf
    __shared__ f16 HL1[2][4 * 128];       // 2KB h1 dbuf   => 92KB total

    const int tid = threadIdx.x;
    const int lane = tid & 63, wid = tid >> 6;
    const int l16 = lane & 15, hi = lane >> 4;
    const int bb0 = blockIdx.x * 4;
    const int mycol = wid * 16 + l16;

    // resident h-side frags for BOTH lstm layers (128 regs, loaded once)
    f16x8 whh0[4][4], whh1[4][4];
    float bg0[4], bg1[4];
#pragma unroll
    for (int g = 0; g < 4; ++g) {
        int n = g * 128 + mycol;
        bg0[g] = bih0[n] + bhh0[n];
        bg1[g] = bih1[n] + bhh1[n];
#pragma unroll
        for (int ki = 0; ki < 4; ++ki) {
            whh0[g][ki] = load8cvt(Whh0 + n * 128 + ki * 32 + hi * 8);
            whh1[g][ki] = load8cvt(Whh1 + n * 128 + ki * 32 + hi * 8);
        }
    }
    // resident conv B-frags (48 regs): wave owns out-cols mycol..mycol+15
    f16x8 cw[3][4];
    {
        const float* wp[3] = { w1p, w2p, w3p };
#pragma unroll
        for (int L = 0; L < 3; ++L)
#pragma unroll
            for (int ki = 0; ki < 4; ++ki)
                cw[L][ki] = load8cvt(wp[L] + mycol * 128 + ki * 32 + hi * 8);
    }

    // conv layer0 per-thread slice + conv biases
    const int col0 = tid & 127;
    const int r0 = tid >> 7;
    float w0c[6], b0c;
#pragma unroll
    for (int k = 0; k < 6; ++k) w0c[k] = w0p[col0 * 6 + k];
    b0c = b0p[col0];
    const float b1c = b1p[mycol], b2c = b2p[mycol], b3c = b3p[mycol];

    for (int i = tid; i < 2 * 4 * 128; i += 512) {
        ((f16*)HL0)[i] = (f16)0.f;
        ((f16*)HL1)[i] = (f16)0.f;
    }

    float c0 = 0.f, h0 = 0.f, c1 = 0.f, h1 = 0.f;
    __syncthreads();

    // conv MFMA layer: A from LDS, resident B-frags
    auto conv_mfma = [&](const f16* Xin, f16* Xout, int L, float bc, int t0pos) {
#pragma unroll
        for (int mt = 0; mt < 2; ++mt) {
            f16x8 af[4];
#pragma unroll
            for (int ki = 0; ki < 4; ++ki)
                af[ki] = lds_rd8(Xin, mt * 16 + l16, ki * 64 + hi * 16);
            f32x4 acc = { bc, bc, bc, bc };
#pragma unroll
            for (int ki = 0; ki < 4; ++ki)
                acc = __builtin_amdgcn_mfma_f32_16x16x32_f16(af[ki], cw[L][ki], acc, 0, 0, 0);
            float pv = 0.f;
            if (t0pos >= 0) pv = posp[(t0pos + mt * 4 + hi) * 128 + mycol];
#pragma unroll
            for (int j = 0; j < 4; ++j)
                lds_wr1(Xout, mt * 16 + hi * 4 + j, mycol, (f16)(gelu_f(acc[j]) + pv));
        }
    };

    // z = A(32x128 LDS) @ Wf^T(512x128 f16 ws, laundered) -> ZXout (f16)
    auto zgemm = [&](const f16* Ain, const f16* Wf0, f16* ZXout) {
        const f16* Wf = launder16(Wf0);
        f16x8 af[2][4];
#pragma unroll
        for (int mt = 0; mt < 2; ++mt)
#pragma unroll
            for (int ki = 0; ki < 4; ++ki)
                af[mt][ki] = lds_rd8(Ain, mt * 16 + l16, ki * 64 + hi * 16);
#pragma unroll
        for (int nt = 0; nt < 4; ++nt) {
            const int n = wid * 64 + nt * 16 + l16;
            f16x8 bf[4];
#pragma unroll
            for (int ki = 0; ki < 4; ++ki)
                bf[ki] = *(const f16x8*)(Wf + n * 128 + ki * 32 + hi * 8);
            f32x4 za0 = { 0.f, 0.f, 0.f, 0.f };
            f32x4 za1 = { 0.f, 0.f, 0.f, 0.f };
#pragma unroll
            for (int ki = 0; ki < 4; ++ki) {
                za0 = __builtin_amdgcn_mfma_f32_16x16x32_f16(af[0][ki], bf[ki], za0, 0, 0, 0);
                za1 = __builtin_amdgcn_mfma_f32_16x16x32_f16(af[1][ki], bf[ki], za1, 0, 0, 0);
            }
#pragma unroll
            for (int j = 0; j < 4; ++j) {
                zx_wr(ZXout, hi * 4 + j, wid * 64 + nt * 16 + l16, (f16)za0[j]);
                zx_wr(ZXout, 16 + hi * 4 + j, wid * 64 + nt * 16 + l16, (f16)za1[j]);
            }
            __builtin_amdgcn_sched_barrier(0);  // keep per-nt loads from hoisting
        }
    };

    // one LSTM step (h-side MFMA + pointwise); t parity selects HL buffer
    auto lstep = [&](f16 (*HLd)[4 * 128], int t, const f16x8 (&whf)[4][4],
                     const float (&bg)[4], const f16* ZXp, int it,
                     float& cc, float& hh, f16* yout) {
        f16x8 ha[4];
#pragma unroll
        for (int ki = 0; ki < 4; ++ki)
            ha[ki] = lds_rd8(HLd[t & 1], l16 >> 2, ki * 64 + hi * 16);
        f32x4 acc[4];
#pragma unroll
        for (int g = 0; g < 4; ++g) {
            f32x4 bv = { bg[g], bg[g], bg[g], bg[g] };
            acc[g] = bv;
        }
#pragma unroll
        for (int ki = 0; ki < 4; ++ki)
#pragma unroll
            for (int g = 0; g < 4; ++g)
                acc[g] = __builtin_amdgcn_mfma_f32_16x16x32_f16(ha[ki], whf[g][ki], acc[g], 0, 0, 0);
        float zi = acc[0][0] + zx_rd(ZXp, it * 4 + hi, 0 + mycol);
        float zf = acc[1][0] + zx_rd(ZXp, it * 4 + hi, 128 + mycol);
        float zg = acc[2][0] + zx_rd(ZXp, it * 4 + hi, 256 + mycol);
        float zo = acc[3][0] + zx_rd(ZXp, it * 4 + hi, 384 + mycol);
        cc = sig_f(zf) * cc + sig_f(zi) * tanh_f(zg);
        hh = sig_f(zo) * tanh_f(cc);
        lds_wr1(HLd[(t + 1) & 1], hi, mycol, (f16)hh);
        if (yout) lds_wr1(yout, it * 4 + hi, mycol, (f16)hh);
    };

    for (int k = 0; k < T_ / CH_; ++k) {
        const int t0 = k * CH_;
        // --- P0: conv layer0 for 8 steps -> XA0 ---
        {
            const float2* sp0 = (const float2*)src + ((size_t)(bb0 + r0) * T_ + t0) * 3;
#pragma unroll
            for (int it = 0; it < CH_; ++it) {
                float2 a = sp0[it * 3 + 0], b = sp0[it * 3 + 1], c2 = sp0[it * 3 + 2];
                float acc = b0c;
                acc = fmaf(a.x, w0c[0], acc);
                acc = fmaf(a.y, w0c[1], acc);
                acc = fmaf(b.x, w0c[2], acc);
                acc = fmaf(b.y, w0c[3], acc);
                acc = fmaf(c2.x, w0c[4], acc);
                acc = fmaf(c2.y, w0c[5], acc);
                lds_wr1(XA0, it * 4 + r0, col0, (f16)gelu_f(acc));
            }
        }
        __syncthreads();
        // --- P1..P3: conv layers 1..3 ---
        conv_mfma(XA0, XA1, 0, b1c, -1);
        __syncthreads();
        conv_mfma(XA1, XA0, 1, b2c, -1);
        __syncthreads();
        conv_mfma(XA0, XA1, 2, b3c, t0);   // + pos_embed
        __syncthreads();
        // --- P4: both z_x GEMMs (YH read here, before P5 rewrites) ---
        zgemm(XA1, Wih0f, ZX0);
        if (k > 0) zgemm(YH, Wih1f, ZX1);
        __syncthreads();
        // --- P5 x8: dual-layer slots ---
        for (int it = 0; it < CH_; ++it) {
            const int t = t0 + it;
            lstep(HL0, t, whh0, bg0, ZX0, it, c0, h0, YH);
            if (k > 0) lstep(HL1, t, whh1, bg1, ZX1, it, c1, h1, nullptr);
            __syncthreads();
        }
    }
    // --- tail: lstm1 on the last chunk's YH (steps 504..511) ---
    zgemm(YH, Wih1f, ZX1);
    __syncthreads();
    for (int it = 0; it < CH_; ++it) {
        lstep(HL1, (T_ - CH_) + it, whh1, bg1, ZX1, it, c1, h1, nullptr);
        __syncthreads();
    }
    hfin[(size_t)(bb0 + hi) * H_ + mycol] = h1;
}

// ---------------------------------------------------------------------------
// K2: head — LayerNorm + Linear(128->32) + GELU + Linear(32->8). 4 rows/block.
// ---------------------------------------------------------------------------
__global__ __launch_bounds__(256) void head_k(
    const float* __restrict__ hfin,
    const float* __restrict__ lng, const float* __restrict__ lnb,
    const float* __restrict__ hw1, const float* __restrict__ hb1,
    const float* __restrict__ hw2, const float* __restrict__ hb2,
    float* __restrict__ outp)
{
    __shared__ float HN[4][128];
    __shared__ float G[4][32];
    const int tid = threadIdx.x, lane = tid & 63, wid = tid >> 6;
    const int b = blockIdx.x * 4 + wid;
    float v0 = hfin[b * 128 + lane], v1 = hfin[b * 128 + 64 + lane];
    float s = v0 + v1;
#pragma unroll
    for (int m = 1; m < 64; m <<= 1) s += __shfl_xor(s, m);
    float mu = s * (1.f / 128.f);
    float d0 = v0 - mu, d1 = v1 - mu;
    float q = d0 * d0 + d1 * d1;
#pragma unroll
    for (int m = 1; m < 64; m <<= 1) q += __shfl_xor(q, m);
    float rs = rsqrtf(q * (1.f / 128.f) + 1e-5f);
    HN[wid][lane] = d0 * rs * lng[lane] + lnb[lane];
    HN[wid][64 + lane] = d1 * rs * lng[64 + lane] + lnb[64 + lane];
    __syncthreads();
    if (tid < 128) {
        int row = tid >> 5, o = tid & 31;
        float a = hb1[o];
#pragma unroll 4
        for (int k = 0; k < 128; ++k) a = fmaf(HN[row][k], hw1[o * 128 + k], a);
        G[row][o] = gelu_f(a);
    }
    __syncthreads();
    if (tid < 32) {
        int row = tid >> 3, oo = tid & 7;
        float a = hb2[oo];
#pragma unroll
        for (int k = 0; k < 32; ++k) a = fmaf(G[row][k], hw2[oo * 32 + k], a);
        outp[(size_t)(blockIdx.x * 4 + row) * 8 + oo] = a;
    }
}

extern "C" void kernel_launch(void* const* d_in, const int* in_sizes, int n_in,
                              void* d_out, int out_size, void* d_ws, size_t ws_size,
                              hipStream_t stream) {
    (void)in_sizes; (void)n_in; (void)out_size; (void)ws_size;
    const float* src  = (const float*)d_in[0];
    const float* w0   = (const float*)d_in[1];
    const float* b0   = (const float*)d_in[2];
    const float* w1   = (const float*)d_in[3];
    const float* b1   = (const float*)d_in[4];
    const float* w2   = (const float*)d_in[5];
    const float* b2   = (const float*)d_in[6];
    const float* w3   = (const float*)d_in[7];
    const float* b3   = (const float*)d_in[8];
    const float* pos  = (const float*)d_in[9];
    const float* Wih0 = (const float*)d_in[10];
    const float* Whh0 = (const float*)d_in[11];
    const float* bih0 = (const float*)d_in[12];
    const float* bhh0 = (const float*)d_in[13];
    const float* Wih1 = (const float*)d_in[14];
    const float* Whh1 = (const float*)d_in[15];
    const float* bih1 = (const float*)d_in[16];
    const float* bhh1 = (const float*)d_in[17];
    const float* lng  = (const float*)d_in[18];
    const float* lnb  = (const float*)d_in[19];
    const float* hw1  = (const float*)d_in[20];
    const float* hb1  = (const float*)d_in[21];
    const float* hw2  = (const float*)d_in[22];
    const float* hb2  = (const float*)d_in[23];
    float* outp = (float*)d_out;

    f16*   Wih0f = (f16*)d_ws;                                // 128KB
    f16*   Wih1f = (f16*)((char*)d_ws + 131072);              // 128KB
    float* hfin  = (float*)((char*)d_ws + 524288);            // (B,H) f32

    prep_k<<<dim3(128), dim3(512), 0, stream>>>(Wih0, Wih1, Wih0f, Wih1f);
    fused_all_k<<<dim3(256), dim3(512), 0, stream>>>(
        src, w0, b0, w1, b1, w2, b2, w3, b3, pos,
        Wih0f, Whh0, bih0, bhh0, Wih1f, Whh1, bih1, bhh1, hfin);
    head_k<<<dim3(256), dim3(256), 0, stream>>>(
        hfin, lng, lnb, hw1, hb1, hw2, hb2, outp);
}